// Round 1
// baseline (753.665 us; speedup 1.0000x reference)
//
#include <hip/hip_runtime.h>
#include <math.h>

// Problem constants
#define BATCH 262144
#define DZ 8
#define DXX 16
#define UU 64

// ws layout (float offsets)
#define WT_OFF  0        // [256][72] transposed combined weights
#define G6_OFF  18432    // [8][8]  C^T diag(1/(R+1e-6)) C
#define G8_OFF  18496    // [8][8]  C^T diag(1/(R+1e-8)) C
#define R6_OFF  18560    // [16] 1/(R+1e-6)
#define R8_OFF  18576    // [16] 1/(R+1e-8)
#define SLR_OFF 18592    // scalar: sum log(R+1e-6)

__device__ __forceinline__ float rcp1(float x) {
    float r = __builtin_amdgcn_rcpf(x);
    return r * (2.0f - x * r);   // one Newton step: ~1e-7 rel err
}
__device__ __forceinline__ float sigm(float x) {
    float e = __expf(-fabsf(x));          // in (0,1], never overflows
    float s = rcp1(1.0f + e);             // sigm(|x|)
    return (x >= 0.0f) ? s : e * s;       // sigm(-|x|) = e*s
}
__device__ __forceinline__ float tanh_f(float x) {
    float e = __expf(-2.0f * fabsf(x));   // in (0,1]
    float t = (1.0f - e) * rcp1(1.0f + e);
    return copysignf(t, x);
}

// ---------------- prep: transpose weights + batch-independent stats ----------
__global__ void prep_kernel(const float* __restrict__ Wk,   // [8][256]
                            const float* __restrict__ Wr,   // [64][256]
                            const float* __restrict__ Cm,   // [16][8]
                            const float* __restrict__ logR, // [16]
                            float* __restrict__ ws) {
    int t = threadIdx.x;   // 0..255, one output column each
    // WT[c][k]: k<8 from W_kernel, else W_recurrent
#pragma unroll
    for (int k = 0; k < 8; ++k)  ws[WT_OFF + t * 72 + k]     = Wk[k * 256 + t];
#pragma unroll
    for (int k = 0; k < 64; ++k) ws[WT_OFF + t * 72 + 8 + k] = Wr[k * 256 + t];

    if (t < 64) {
        int k = t >> 3, l = t & 7;
        float g6 = 0.0f, g8 = 0.0f;
        for (int i = 0; i < 16; ++i) {
            float R  = expf(logR[i]);
            float cc = Cm[i * 8 + k] * Cm[i * 8 + l];
            g6 += cc / (R + 1e-6f);
            g8 += cc / (R + 1e-8f);
        }
        ws[G6_OFF + t] = g6;
        ws[G8_OFF + t] = g8;
    } else if (t < 80) {
        int i = t - 64;
        float R = expf(logR[i]);
        ws[R6_OFF + i] = 1.0f / (R + 1e-6f);
        ws[R8_OFF + i] = 1.0f / (R + 1e-8f);
    } else if (t == 80) {
        float s = 0.0f;
        for (int i = 0; i < 16; ++i) s += logf(expf(logR[i]) + 1e-6f);
        ws[SLR_OFF] = s;
    }
}

// ---------------- main fused kernel: one thread per batch element ------------
__global__ __launch_bounds__(256)
void fused_kernel(const float* __restrict__ h_in,
                  const float* __restrict__ c_in,
                  const float* __restrict__ z_prev,
                  const float* __restrict__ x_in,
                  const float* __restrict__ b_lstm,
                  const float* __restrict__ W_mu,
                  const float* __restrict__ b_mu,
                  const float* __restrict__ W_ls,
                  const float* __restrict__ b_ls,
                  const float* __restrict__ Cm,
                  const float* __restrict__ b_em,
                  const float* __restrict__ ws,
                  float* __restrict__ out) {
    const int e = blockIdx.x * 256 + threadIdx.x;
    if (e >= BATCH) return;

    const float* WT = ws + WT_OFF;
    const float* G6 = ws + G6_OFF;
    const float* G8 = ws + G8_OFF;
    const float* r6 = ws + R6_OFF;
    const float* r8 = ws + R8_OFF;
    const float  slr = ws[SLR_OFF];

    // ---- load per-element state: ha = [z_prev(8) | h(64)] ----
    float ha[72];
    {
        const float4* z4 = (const float4*)(z_prev + (size_t)e * 8);
        float4 a = z4[0], b = z4[1];
        ha[0] = a.x; ha[1] = a.y; ha[2] = a.z; ha[3] = a.w;
        ha[4] = b.x; ha[5] = b.y; ha[6] = b.z; ha[7] = b.w;
    }
    {
        const float4* h4 = (const float4*)(h_in + (size_t)e * 64);
#pragma unroll
        for (int q = 0; q < 16; ++q) {
            float4 v = h4[q];
            ha[8 + 4 * q + 0] = v.x; ha[8 + 4 * q + 1] = v.y;
            ha[8 + 4 * q + 2] = v.z; ha[8 + 4 * q + 3] = v.w;
        }
    }

    float mu[8], lsg[8];
#pragma unroll
    for (int d = 0; d < 8; ++d) { mu[d] = b_mu[d]; lsg[d] = b_ls[d]; }

    float* outH = out + (size_t)BATCH * 73  + (size_t)e * 64;
    float* outC = out + (size_t)BATCH * 137 + (size_t)e * 64;

    // ---- LSTM: 4 gate dot-products per unit, weights via scalar (uniform) loads
#pragma unroll 1
    for (int u = 0; u < 64; ++u) {
        float zi = b_lstm[u], zf = b_lstm[64 + u], zg = b_lstm[128 + u], zo = b_lstm[192 + u];
        const float* wi = WT + (size_t)u * 72;
        const float* wf = WT + (size_t)(64 + u) * 72;
        const float* wg = WT + (size_t)(128 + u) * 72;
        const float* wo = WT + (size_t)(192 + u) * 72;
#pragma unroll
        for (int k = 0; k < 72; ++k) {
            float hv = ha[k];
            zi = fmaf(hv, wi[k], zi);
            zf = fmaf(hv, wf[k], zf);
            zg = fmaf(hv, wg[k], zg);
            zo = fmaf(hv, wo[k], zo);
        }
        float cold = c_in[(size_t)e * 64 + u];
        float cnew = sigm(zf) * cold + sigm(zi) * tanh_f(zg);
        float hnew = sigm(zo) * tanh_f(cnew);
        outH[u] = hnew;
        outC[u] = cnew;
#pragma unroll
        for (int d = 0; d < 8; ++d) {
            mu[d]  = fmaf(hnew, W_mu[u * 8 + d], mu[d]);
            lsg[d] = fmaf(hnew, W_ls[u * 8 + d], lsg[d]);
        }
    }

    // ---- transition params ----
    float sig[8], Sinv[8];
#pragma unroll
    for (int d = 0; d < 8; ++d) {
        float l = fminf(fmaxf(lsg[d], -5.0f), 3.0f);
        float s = __expf(l);
        sig[d]  = s;
        Sinv[d] = rcp1(s * s + 1e-8f);
    }

    // ---- x_t, pred_mean, projections t6 (for alpha) and t8 (for gamma info) ----
    float xv[16];
    {
        const float4* x4 = (const float4*)(x_in + (size_t)e * 16);
#pragma unroll
        for (int q = 0; q < 4; ++q) {
            float4 v = x4[q];
            xv[4 * q + 0] = v.x; xv[4 * q + 1] = v.y;
            xv[4 * q + 2] = v.z; xv[4 * q + 3] = v.w;
        }
    }
    float t6[8], t8[8];
#pragma unroll
    for (int k = 0; k < 8; ++k) { t6[k] = 0.0f; t8[k] = 0.0f; }
    float qdr = 0.0f;
#pragma unroll
    for (int i = 0; i < 16; ++i) {
        float pm = b_em[i];
#pragma unroll
        for (int d = 0; d < 8; ++d) pm = fmaf(mu[d], Cm[i * 8 + d], pm);
        float df = xv[i] - pm;           // x - pred_mean
        float xe = xv[i] - b_em[i];      // x - b_emission
        float a6 = df * r6[i];
        float a8 = xe * r8[i];
        qdr = fmaf(df, a6, qdr);
#pragma unroll
        for (int k = 0; k < 8; ++k) {
            t6[k] = fmaf(a6, Cm[i * 8 + k], t6[k]);
            t8[k] = fmaf(a8, Cm[i * 8 + k], t8[k]);
        }
    }

    // ---- alpha via Woodbury: M = I + sig sig^T (.) G6 ; chol; mahal/logdet ----
    float M[8][8];
#pragma unroll
    for (int k = 0; k < 8; ++k)
#pragma unroll
        for (int l = 0; l <= k; ++l)
            M[k][l] = ((k == l) ? 1.0f : 0.0f) + sig[k] * sig[l] * G6[k * 8 + l];

    float ldia[8];
    float logdetM = 0.0f;
#pragma unroll
    for (int k = 0; k < 8; ++k) {
        float d = M[k][k];
#pragma unroll
        for (int j = 0; j < k; ++j) d = fmaf(-M[k][j], M[k][j], d);
        float l = sqrtf(d);
        logdetM += __logf(d);            // 2*log(l)
        float li = rcp1(l);
        M[k][k] = l; ldia[k] = li;
#pragma unroll
        for (int i = k + 1; i < 8; ++i) {
            float s = M[i][k];
#pragma unroll
            for (int j = 0; j < k; ++j) s = fmaf(-M[i][j], M[k][j], s);
            M[i][k] = s * li;
        }
    }
    // forward solve w = L^-1 (sig .* t6); mahal = qdr - ||w||^2
    float w[8];
    float ssq = 0.0f;
#pragma unroll
    for (int k = 0; k < 8; ++k) {
        float s = sig[k] * t6[k];
#pragma unroll
        for (int j = 0; j < k; ++j) s = fmaf(-M[k][j], w[j], s);
        w[k] = s * ldia[k];
        ssq  = fmaf(w[k], w[k], ssq);
    }
    float mahal  = qdr - ssq;
    float logdet = slr + logdetM;
    float alpha  = -0.5f * (mahal + logdet + 29.40603306254952f); // 16*ln(2pi)

    // ---- gamma: V = (diag(Sinv)+1e-6 I + CtRinvC)^-1 via chol + tri-inverse ----
    float Vi[8][8];
#pragma unroll
    for (int k = 0; k < 8; ++k)
#pragma unroll
        for (int l = 0; l <= k; ++l)
            Vi[k][l] = G8[k * 8 + l] + ((k == l) ? (Sinv[k] + 1e-6f) : 0.0f);

    float vdia[8];
#pragma unroll
    for (int k = 0; k < 8; ++k) {
        float d = Vi[k][k];
#pragma unroll
        for (int j = 0; j < k; ++j) d = fmaf(-Vi[k][j], Vi[k][j], d);
        float l = sqrtf(d);
        float li = rcp1(l);
        Vi[k][k] = l; vdia[k] = li;
#pragma unroll
        for (int i = k + 1; i < 8; ++i) {
            float s = Vi[i][k];
#pragma unroll
            for (int j = 0; j < k; ++j) s = fmaf(-Vi[i][j], Vi[k][j], s);
            Vi[i][k] = s * li;
        }
    }
    // J = L^-1 (lower), stored into M (dead)
#pragma unroll
    for (int k = 0; k < 8; ++k) {
        M[k][k] = vdia[k];
#pragma unroll
        for (int i = k + 1; i < 8; ++i) {
            float s = 0.0f;
#pragma unroll
            for (int j = k; j < i; ++j) s = fmaf(Vi[i][j], M[j][k], s);
            M[i][k] = -s * vdia[i];
        }
    }
    float info[8];
#pragma unroll
    for (int k = 0; k < 8; ++k) info[k] = fmaf(Sinv[k], mu[k], t8[k]);

    // V = J^T J  (store rows), gamma = V @ info
    float* outV = out + (size_t)BATCH * 9 + (size_t)e * 64;
    float gam[8];
#pragma unroll
    for (int a = 0; a < 8; ++a) gam[a] = 0.0f;
#pragma unroll
    for (int a = 0; a < 8; ++a) {
        float vrow[8];
#pragma unroll
        for (int b = 0; b < 8; ++b) {
            int m0 = (a > b) ? a : b;
            float s = 0.0f;
#pragma unroll
            for (int i = 0; i < 8; ++i)
                if (i >= m0) s = fmaf(M[i][a], M[i][b], s);
            vrow[b] = s;
            gam[a]  = fmaf(s, info[b], gam[a]);
        }
        *(float4*)(outV + a * 8)     = make_float4(vrow[0], vrow[1], vrow[2], vrow[3]);
        *(float4*)(outV + a * 8 + 4) = make_float4(vrow[4], vrow[5], vrow[6], vrow[7]);
    }

    out[e] = alpha;
    float4* outG = (float4*)(out + (size_t)BATCH + (size_t)e * 8);
    outG[0] = make_float4(gam[0], gam[1], gam[2], gam[3]);
    outG[1] = make_float4(gam[4], gam[5], gam[6], gam[7]);
}

extern "C" void kernel_launch(void* const* d_in, const int* in_sizes, int n_in,
                              void* d_out, int out_size, void* d_ws, size_t ws_size,
                              hipStream_t stream) {
    const float* h    = (const float*)d_in[0];
    const float* c    = (const float*)d_in[1];
    const float* zp   = (const float*)d_in[2];
    const float* xt   = (const float*)d_in[3];
    const float* Wk   = (const float*)d_in[4];
    const float* Wr   = (const float*)d_in[5];
    const float* bl   = (const float*)d_in[6];
    const float* Wmu  = (const float*)d_in[7];
    const float* bmu  = (const float*)d_in[8];
    const float* Wls  = (const float*)d_in[9];
    const float* bls  = (const float*)d_in[10];
    const float* Cm   = (const float*)d_in[11];
    const float* bem  = (const float*)d_in[12];
    const float* logR = (const float*)d_in[13];
    float* ws  = (float*)d_ws;
    float* out = (float*)d_out;

    hipLaunchKernelGGL(prep_kernel, dim3(1), dim3(256), 0, stream, Wk, Wr, Cm, logR, ws);
    hipLaunchKernelGGL(fused_kernel, dim3(BATCH / 256), dim3(256), 0, stream,
                       h, c, zp, xt, bl, Wmu, bmu, Wls, bls, Cm, bem, ws, out);
}

// Round 2
// 667.097 us; speedup vs baseline: 1.1298x; 1.1298x over previous
//
#include <hip/hip_runtime.h>
#include <math.h>

// Problem constants
#define BATCH 262144
#define DZ 8
#define DXX 16
#define UU 64

// ws layout (float offsets)
#define WT_OFF  0        // [256][72] transposed combined weights
#define G6_OFF  18432    // [8][8]  C^T diag(1/(R+1e-6)) C
#define G8_OFF  18496    // [8][8]  C^T diag(1/(R+1e-8)) C
#define R6_OFF  18560    // [16] 1/(R+1e-6)
#define R8_OFF  18576    // [16] 1/(R+1e-8)
#define SLR_OFF 18592    // scalar: sum log(R+1e-6)

__device__ __forceinline__ float rcp1(float x) {
    float r = __builtin_amdgcn_rcpf(x);
    return r * (2.0f - x * r);   // one Newton step: ~1e-7 rel err
}
__device__ __forceinline__ float sigm(float x) {
    float e = __expf(-fabsf(x));          // in (0,1], never overflows
    float s = rcp1(1.0f + e);             // sigm(|x|)
    return (x >= 0.0f) ? s : e * s;       // sigm(-|x|) = e*s
}
__device__ __forceinline__ float tanh_f(float x) {
    float e = __expf(-2.0f * fabsf(x));   // in (0,1]
    float t = (1.0f - e) * rcp1(1.0f + e);
    return copysignf(t, x);
}

// ---------------- prep: transpose weights + batch-independent stats ----------
__global__ void prep_kernel(const float* __restrict__ Wk,   // [8][256]
                            const float* __restrict__ Wr,   // [64][256]
                            const float* __restrict__ Cm,   // [16][8]
                            const float* __restrict__ logR, // [16]
                            float* __restrict__ ws) {
    int t = threadIdx.x;   // 0..255, one output column each
#pragma unroll
    for (int k = 0; k < 8; ++k)  ws[WT_OFF + t * 72 + k]     = Wk[k * 256 + t];
#pragma unroll
    for (int k = 0; k < 64; ++k) ws[WT_OFF + t * 72 + 8 + k] = Wr[k * 256 + t];

    if (t < 64) {
        int k = t >> 3, l = t & 7;
        float g6 = 0.0f, g8 = 0.0f;
        for (int i = 0; i < 16; ++i) {
            float R  = expf(logR[i]);
            float cc = Cm[i * 8 + k] * Cm[i * 8 + l];
            g6 += cc / (R + 1e-6f);
            g8 += cc / (R + 1e-8f);
        }
        ws[G6_OFF + t] = g6;
        ws[G8_OFF + t] = g8;
    } else if (t < 80) {
        int i = t - 64;
        float R = expf(logR[i]);
        ws[R6_OFF + i] = 1.0f / (R + 1e-6f);
        ws[R8_OFF + i] = 1.0f / (R + 1e-8f);
    } else if (t == 80) {
        float s = 0.0f;
        for (int i = 0; i < 16; ++i) s += logf(expf(logR[i]) + 1e-6f);
        ws[SLR_OFF] = s;
    }
}

// ---------------- main fused kernel ------------------------------------------
// Block = 256 threads = 256 batch elements, processed as 4 tiles of 64.
// LDS layout is [feature][element] (stride 65/257) so compute-phase reads are
// lane-stride-1 (conflict-free) and global I/O is coalesced float4.
__global__ __launch_bounds__(256)
void fused_kernel(const float* __restrict__ h_in,
                  const float* __restrict__ c_in,
                  const float* __restrict__ z_prev,
                  const float* __restrict__ x_in,
                  const float* __restrict__ b_lstm,
                  const float* __restrict__ W_mu,
                  const float* __restrict__ b_mu,
                  const float* __restrict__ W_ls,
                  const float* __restrict__ b_ls,
                  const float* __restrict__ Cm,
                  const float* __restrict__ b_em,
                  const float* __restrict__ ws,
                  float* __restrict__ out) {
    __shared__ float ha_lds[72 * 65];   // [k][e]  k<8: z, k>=8: h; later h_new rows 0..63; later V chunk buf
    __shared__ float c_lds[64 * 65];    // [u][e]  c_old, overwritten in place by c_new
    __shared__ float muls[16 * 257];    // [d][e256]  d 0..7: mu, 8..15: log_sigma (pre-clip)

    const int t    = threadIdx.x;
    const int lane = t & 63;
    const int wv   = t >> 6;                                  // 0..3
    const int wvu  = __builtin_amdgcn_readfirstlane(wv);      // wave-uniform copy
    const int blk  = blockIdx.x;

    const float* WT = ws + WT_OFF;

    // ================= LSTM + mu/lsg over 4 tiles of 64 elements =============
    for (int tile = 0; tile < 4; ++tile) {
        const size_t E0 = (size_t)blk * 256 + (size_t)tile * 64;   // first element of tile

        // ---- stage h, c, z (coalesced global -> LDS transpose) ----
#pragma unroll
        for (int i = 0; i < 4; ++i) {
            int g = i * 1024 + t * 4;      // 0..4095 over block
            int e = g >> 6, u = g & 63;
            float4 hv = *(const float4*)(h_in + E0 * 64 + g);
            float4 cv = *(const float4*)(c_in + E0 * 64 + g);
            ha_lds[(8 + u + 0) * 65 + e] = hv.x;
            ha_lds[(8 + u + 1) * 65 + e] = hv.y;
            ha_lds[(8 + u + 2) * 65 + e] = hv.z;
            ha_lds[(8 + u + 3) * 65 + e] = hv.w;
            c_lds[(u + 0) * 65 + e] = cv.x;
            c_lds[(u + 1) * 65 + e] = cv.y;
            c_lds[(u + 2) * 65 + e] = cv.z;
            c_lds[(u + 3) * 65 + e] = cv.w;
        }
        if (t < 128) {
            int g = t * 4;                 // 0..511
            int e = g >> 3, d = g & 7;
            float4 zv = *(const float4*)(z_prev + E0 * 8 + g);
            ha_lds[(d + 0) * 65 + e] = zv.x;
            ha_lds[(d + 1) * 65 + e] = zv.y;
            ha_lds[(d + 2) * 65 + e] = zv.z;
            ha_lds[(d + 3) * 65 + e] = zv.w;
        }
        __syncthreads();

        // ---- each thread: element `lane`, units [wvu*16, wvu*16+16) ----
        float ha[72];
#pragma unroll
        for (int k = 0; k < 72; ++k) ha[k] = ha_lds[k * 65 + lane];
        __syncthreads();   // before overwriting ha_lds rows with h_new

#pragma unroll 1
        for (int uu = 0; uu < 16; ++uu) {
            int u = wvu * 16 + uu;         // wave-uniform
            float zi = b_lstm[u], zf = b_lstm[64 + u], zg = b_lstm[128 + u], zo = b_lstm[192 + u];
            const float* wi = WT + (size_t)u * 72;
            const float* wf = WT + (size_t)(64 + u) * 72;
            const float* wg = WT + (size_t)(128 + u) * 72;
            const float* wo = WT + (size_t)(192 + u) * 72;
#pragma unroll
            for (int k = 0; k < 72; ++k) {
                float hv = ha[k];
                zi = fmaf(hv, wi[k], zi);
                zf = fmaf(hv, wf[k], zf);
                zg = fmaf(hv, wg[k], zg);
                zo = fmaf(hv, wo[k], zo);
            }
            float cold = c_lds[u * 65 + lane];
            float cnew = sigm(zf) * cold + sigm(zi) * tanh_f(zg);
            float hnew = sigm(zo) * tanh_f(cnew);
            c_lds[u * 65 + lane]  = cnew;   // in place: only this thread touches the slot
            ha_lds[u * 65 + lane] = hnew;   // rows 0..63 now hold h_new
        }
        __syncthreads();

        // ---- mu / log_sigma from LDS h_new: thread = (elem lane, d-pair wvu) ----
        {
            int d0 = wvu * 2;
            float m0 = b_mu[d0], m1 = b_mu[d0 + 1];
            float l0 = b_ls[d0], l1 = b_ls[d0 + 1];
#pragma unroll
            for (int u = 0; u < 64; ++u) {
                float hv = ha_lds[u * 65 + lane];
                m0 = fmaf(hv, W_mu[u * 8 + d0],     m0);
                m1 = fmaf(hv, W_mu[u * 8 + d0 + 1], m1);
                l0 = fmaf(hv, W_ls[u * 8 + d0],     l0);
                l1 = fmaf(hv, W_ls[u * 8 + d0 + 1], l1);
            }
            int col = tile * 64 + lane;
            muls[(d0 + 0) * 257 + col] = m0;
            muls[(d0 + 1) * 257 + col] = m1;
            muls[(8 + d0 + 0) * 257 + col] = l0;
            muls[(8 + d0 + 1) * 257 + col] = l1;
        }

        // ---- coalesced write-out of h_new / c_new ----
        {
            float* outH = out + (size_t)BATCH * 73  + E0 * 64;
            float* outC = out + (size_t)BATCH * 137 + E0 * 64;
#pragma unroll
            for (int i = 0; i < 4; ++i) {
                int g = i * 1024 + t * 4;
                int e = g >> 6, u = g & 63;
                float4 hv = make_float4(ha_lds[(u + 0) * 65 + e], ha_lds[(u + 1) * 65 + e],
                                        ha_lds[(u + 2) * 65 + e], ha_lds[(u + 3) * 65 + e]);
                float4 cv = make_float4(c_lds[(u + 0) * 65 + e], c_lds[(u + 1) * 65 + e],
                                        c_lds[(u + 2) * 65 + e], c_lds[(u + 3) * 65 + e]);
                *(float4*)(outH + g) = hv;
                *(float4*)(outC + g) = cv;
            }
        }
        __syncthreads();   // before next tile overwrites ha_lds / c_lds
    }

    // ================= per-element tail: element = blk*256 + t ================
    const float* G6 = ws + G6_OFF;
    const float* G8 = ws + G8_OFF;
    const float* r6 = ws + R6_OFF;
    const float* r8 = ws + R8_OFF;
    const float  slr = ws[SLR_OFF];
    const size_t e = (size_t)blk * 256 + t;

    float mu[8], lsg[8];
#pragma unroll
    for (int d = 0; d < 8; ++d) {
        mu[d]  = muls[d * 257 + t];
        lsg[d] = muls[(8 + d) * 257 + t];
    }

    float sig[8], Sinv[8];
#pragma unroll
    for (int d = 0; d < 8; ++d) {
        float l = fminf(fmaxf(lsg[d], -5.0f), 3.0f);
        float s = __expf(l);
        sig[d]  = s;
        Sinv[d] = rcp1(s * s + 1e-8f);
    }

    float xv[16];
    {
        const float4* x4 = (const float4*)(x_in + e * 16);
#pragma unroll
        for (int q = 0; q < 4; ++q) {
            float4 v = x4[q];
            xv[4 * q + 0] = v.x; xv[4 * q + 1] = v.y;
            xv[4 * q + 2] = v.z; xv[4 * q + 3] = v.w;
        }
    }

    float t6[8], t8[8];
#pragma unroll
    for (int k = 0; k < 8; ++k) { t6[k] = 0.0f; t8[k] = 0.0f; }
    float qdr = 0.0f;
#pragma unroll
    for (int i = 0; i < 16; ++i) {
        float pm = b_em[i];
#pragma unroll
        for (int d = 0; d < 8; ++d) pm = fmaf(mu[d], Cm[i * 8 + d], pm);
        float df = xv[i] - pm;
        float xe = xv[i] - b_em[i];
        float a6 = df * r6[i];
        float a8 = xe * r8[i];
        qdr = fmaf(df, a6, qdr);
#pragma unroll
        for (int k = 0; k < 8; ++k) {
            t6[k] = fmaf(a6, Cm[i * 8 + k], t6[k]);
            t8[k] = fmaf(a8, Cm[i * 8 + k], t8[k]);
        }
    }

    // ---- alpha via Woodbury: M = I + sig sig^T (.) G6 ----
    float M[8][8];
#pragma unroll
    for (int k = 0; k < 8; ++k)
#pragma unroll
        for (int l = 0; l <= k; ++l)
            M[k][l] = ((k == l) ? 1.0f : 0.0f) + sig[k] * sig[l] * G6[k * 8 + l];

    float ldia[8];
    float logdetM = 0.0f;
#pragma unroll
    for (int k = 0; k < 8; ++k) {
        float d = M[k][k];
#pragma unroll
        for (int j = 0; j < k; ++j) d = fmaf(-M[k][j], M[k][j], d);
        float l = sqrtf(d);
        logdetM += __logf(d);
        float li = rcp1(l);
        M[k][k] = l; ldia[k] = li;
#pragma unroll
        for (int i = k + 1; i < 8; ++i) {
            float s = M[i][k];
#pragma unroll
            for (int j = 0; j < k; ++j) s = fmaf(-M[i][j], M[k][j], s);
            M[i][k] = s * li;
        }
    }
    float w[8];
    float ssq = 0.0f;
#pragma unroll
    for (int k = 0; k < 8; ++k) {
        float s = sig[k] * t6[k];
#pragma unroll
        for (int j = 0; j < k; ++j) s = fmaf(-M[k][j], w[j], s);
        w[k] = s * ldia[k];
        ssq  = fmaf(w[k], w[k], ssq);
    }
    float mahal  = qdr - ssq;
    float logdet = slr + logdetM;
    float alpha  = -0.5f * (mahal + logdet + 29.40603306254952f); // 16*ln(2pi)

    // ---- gamma: V = (diag(Sinv)+1e-6 I + G8)^-1 via chol + tri-inverse ----
    float Vi[8][8];
#pragma unroll
    for (int k = 0; k < 8; ++k)
#pragma unroll
        for (int l = 0; l <= k; ++l)
            Vi[k][l] = G8[k * 8 + l] + ((k == l) ? (Sinv[k] + 1e-6f) : 0.0f);

    float vdia[8];
#pragma unroll
    for (int k = 0; k < 8; ++k) {
        float d = Vi[k][k];
#pragma unroll
        for (int j = 0; j < k; ++j) d = fmaf(-Vi[k][j], Vi[k][j], d);
        float l = sqrtf(d);
        float li = rcp1(l);
        Vi[k][k] = l; vdia[k] = li;
#pragma unroll
        for (int i = k + 1; i < 8; ++i) {
            float s = Vi[i][k];
#pragma unroll
            for (int j = 0; j < k; ++j) s = fmaf(-Vi[i][j], Vi[k][j], s);
            Vi[i][k] = s * li;
        }
    }
    // J = L^-1 (lower), stored into M (dead)
#pragma unroll
    for (int k = 0; k < 8; ++k) {
        M[k][k] = vdia[k];
#pragma unroll
        for (int i = k + 1; i < 8; ++i) {
            float s = 0.0f;
#pragma unroll
            for (int j = k; j < i; ++j) s = fmaf(Vi[i][j], M[j][k], s);
        M[i][k] = -s * vdia[i];
        }
    }
    float info[8];
#pragma unroll
    for (int k = 0; k < 8; ++k) info[k] = fmaf(Sinv[k], mu[k], t8[k]);

    // ---- V = J^T J + gamma, staged through LDS (reuse ha_lds) in 4 chunks ----
    __syncthreads();   // muls reads done; ha_lds free for reuse
#pragma unroll 1
    for (int ch = 0; ch < 4; ++ch) {
        if (wv == ch) {
            float gam[8];
#pragma unroll
            for (int a = 0; a < 8; ++a) gam[a] = 0.0f;
#pragma unroll
            for (int a = 0; a < 8; ++a) {
#pragma unroll
                for (int b = 0; b < 8; ++b) {
                    int m0 = (a > b) ? a : b;
                    float s = 0.0f;
#pragma unroll
                    for (int i = 0; i < 8; ++i)
                        if (i >= m0) s = fmaf(M[i][a], M[i][b], s);
                    ha_lds[(a * 8 + b) * 65 + lane] = s;   // V chunk buffer
                    gam[a] = fmaf(s, info[b], gam[a]);
                }
            }
            out[e] = alpha;
            float4* outG = (float4*)(out + (size_t)BATCH + e * 8);
            outG[0] = make_float4(gam[0], gam[1], gam[2], gam[3]);
            outG[1] = make_float4(gam[4], gam[5], gam[6], gam[7]);
        }
        __syncthreads();
        // coalesced copy of this chunk's V (64 elems x 64 floats)
        {
            float* outV = out + (size_t)BATCH * 9 + ((size_t)blk * 256 + (size_t)ch * 64) * 64;
#pragma unroll
            for (int i = 0; i < 4; ++i) {
                int g = i * 1024 + t * 4;
                int ee = g >> 6, j = g & 63;
                float4 v = make_float4(ha_lds[(j + 0) * 65 + ee], ha_lds[(j + 1) * 65 + ee],
                                       ha_lds[(j + 2) * 65 + ee], ha_lds[(j + 3) * 65 + ee]);
                *(float4*)(outV + g) = v;
            }
        }
        __syncthreads();
    }
}

extern "C" void kernel_launch(void* const* d_in, const int* in_sizes, int n_in,
                              void* d_out, int out_size, void* d_ws, size_t ws_size,
                              hipStream_t stream) {
    const float* h    = (const float*)d_in[0];
    const float* c    = (const float*)d_in[1];
    const float* zp   = (const float*)d_in[2];
    const float* xt   = (const float*)d_in[3];
    const float* Wk   = (const float*)d_in[4];
    const float* Wr   = (const float*)d_in[5];
    const float* bl   = (const float*)d_in[6];
    const float* Wmu  = (const float*)d_in[7];
    const float* bmu  = (const float*)d_in[8];
    const float* Wls  = (const float*)d_in[9];
    const float* bls  = (const float*)d_in[10];
    const float* Cm   = (const float*)d_in[11];
    const float* bem  = (const float*)d_in[12];
    const float* logR = (const float*)d_in[13];
    float* ws  = (float*)d_ws;
    float* out = (float*)d_out;

    hipLaunchKernelGGL(prep_kernel, dim3(1), dim3(256), 0, stream, Wk, Wr, Cm, logR, ws);
    hipLaunchKernelGGL(fused_kernel, dim3(BATCH / 256), dim3(256), 0, stream,
                       h, c, zp, xt, bl, Wmu, bmu, Wls, bls, Cm, bem, ws, out);
}